// Round 3
// baseline (553.350 us; speedup 1.0000x reference)
//
#include <hip/hip_runtime.h>

#define NN 10000
#define EE 100000
#define CC 32
#define GG 64
#define EPSV 1e-5f
#define PROW 33            // 32 h-rows + 1 bias row
#define PSTRIDE (PROW*32)  // 1056 floats per node
#define NT 20              // nodes per precompute block (500 blocks, ~2/CU)

// ---------------- degree / pool-count histograms ----------------
__global__ void k_degrees(const int* __restrict__ ei, const int* __restrict__ batch,
                          int* __restrict__ cnt, int* __restrict__ pcnt) {
    int t = blockIdx.x * blockDim.x + threadIdx.x;
    if (t < EE) atomicAdd(&cnt[ei[EE + t]], 1);   // dst in-degree
    if (t < NN) atomicAdd(&pcnt[batch[t]], 1);    // nodes per graph
}

// ---------------- P[n, c*32+o] = sum_i x[n,i]*w2[c,i*32+o]  (c=0..31) ----------------
// R2: register-resident weights. Thread t owns slots {t, t+256, t+512, t+768}:
// same o = t&31, c = (t>>5)+8k -> 128 weight VGPRs loaded once per block,
// amortized over NT nodes. x-tile in LDS, read as broadcast float4.
__global__ __launch_bounds__(256, 2) void k_precompute(const float* __restrict__ x,
        const float* __restrict__ w2, float* __restrict__ P) {
    __shared__ float xs[NT][32];
    int t = threadIdx.x;
    int o = t & 31, c0 = t >> 5;
    int n0 = blockIdx.x * NT;

    // stage x tile (NT*32 = 640 floats)
    for (int idx = t; idx < NT * 32; idx += 256) xs[idx >> 5][idx & 31] = x[n0 * 32 + idx];

    // load 4 weight columns into registers (once per block)
    float wv[4][32];
    #pragma unroll
    for (int k = 0; k < 4; k++) {
        const float* wrow = w2 + (size_t)(c0 + 8 * k) * 1024 + o;
        #pragma unroll
        for (int i = 0; i < 32; i++) wv[k][i] = wrow[i * 32];
    }
    __syncthreads();

    for (int n = 0; n < NT; n++) {
        const float4* xv4 = (const float4*)(&xs[n][0]);
        float4 q[8];
        #pragma unroll
        for (int j = 0; j < 8; j++) q[j] = xv4[j];   // 8x ds_read_b128 broadcast
        float acc[4] = {0.f, 0.f, 0.f, 0.f};
        #pragma unroll
        for (int j = 0; j < 8; j++) {
            float xi0 = q[j].x, xi1 = q[j].y, xi2 = q[j].z, xi3 = q[j].w;
            #pragma unroll
            for (int k = 0; k < 4; k++) {
                acc[k] += xi0 * wv[k][4 * j + 0];
                acc[k] += xi1 * wv[k][4 * j + 1];
                acc[k] += xi2 * wv[k][4 * j + 2];
                acc[k] += xi3 * wv[k][4 * j + 3];
            }
        }
        float* Pn = P + (size_t)(n0 + n) * PSTRIDE;
        #pragma unroll
        for (int k = 0; k < 4; k++) Pn[t + 256 * k] = acc[k];  // wave-coalesced
    }
}

// ---------------- bias row: P[n, 1024+o] = sum_i x[n,i]*b2[i*32+o] ----------------
__global__ __launch_bounds__(256) void k_biasrow(const float* __restrict__ x,
        const float* __restrict__ b2, float* __restrict__ P) {
    int gid = blockIdx.x * 256 + threadIdx.x;
    int n = gid >> 5, o = gid & 31;
    if (n >= NN) return;
    float acc = 0.f;
    #pragma unroll
    for (int i = 0; i < 32; i++) acc += x[n * 32 + i] * b2[i * 32 + o];
    P[(size_t)n * PSTRIDE + 1024 + o] = acc;
}

// ---------------- per-edge message + atomic scatter to agg[dst] ----------------
// half-wave (32 lanes) per edge; lane = output channel o; h computed on the fly
__global__ __launch_bounds__(256) void k_message(const float* __restrict__ edge_attr,
        const float* __restrict__ w1, const float* __restrict__ b1,
        const float* __restrict__ P, const int* __restrict__ ei,
        float* __restrict__ agg) {
    int t = threadIdx.x;
    int e = blockIdx.x * 8 + (t >> 5);
    int o = t & 31;
    if (e >= EE) return;
    const float* ea = edge_attr + (size_t)e * 4;
    float h = ea[0] * w1[o] + ea[1] * w1[32 + o] + ea[2] * w1[64 + o] + ea[3] * w1[96 + o] + b1[o];
    h = fmaxf(h, 0.f);
    int src = ei[e], dst = ei[EE + e];
    const float* Pn = P + (size_t)src * PSTRIDE;
    float msg = Pn[32 * 32 + o];          // bias row
    #pragma unroll
    for (int c = 0; c < 32; c++) {
        float hc = __shfl(h, c, 32);      // broadcast h[c] within the 32-lane half
        msg += hc * Pn[c * 32 + o];
    }
    atomicAdd(&agg[(size_t)dst * 32 + o], msg);
}

// ---------------- combine: agg/cnt + x@root + bias -> BN -> ReLU ----------------
__global__ __launch_bounds__(256) void k_combine(const float* __restrict__ x_in,
        const float* __restrict__ agg, const int* __restrict__ cnt,
        const float* __restrict__ root, const float* __restrict__ bias,
        const float* __restrict__ bng, const float* __restrict__ bnb,
        const float* __restrict__ bnm, const float* __restrict__ bnv,
        float* __restrict__ x_out, float* __restrict__ psum,
        const int* __restrict__ batch) {
    __shared__ float xs[8][32];
    int t = threadIdx.x;
    int n0 = blockIdx.x * 8;
    xs[t >> 5][t & 31] = x_in[n0 * 32 + t];
    __syncthreads();
    int k = t >> 5, o = t & 31, n = n0 + k;
    float r = bias[o];
    #pragma unroll
    for (int i = 0; i < 32; i++) r += xs[k][i] * root[i * 32 + o];
    float a = agg[(size_t)n * 32 + o] / fmaxf((float)cnt[n], 1.f);
    float val = a + r;
    val = (val - bnm[o]) * rsqrtf(bnv[o] + EPSV) * bng[o] + bnb[o];
    val = fmaxf(val, 0.f);
    if (x_out) x_out[(size_t)n * 32 + o] = val;
    if (psum) atomicAdd(&psum[(size_t)batch[n] * 32 + o], val);
}

// ---------------- global mean pool + readout MLP (LDS-staged, R1 fix) ----------------
__global__ __launch_bounds__(256) void k_readout(const float* __restrict__ psum,
        const int* __restrict__ pcnt,
        const float* __restrict__ r1w, const float* __restrict__ r1b,
        const float* __restrict__ r2w, const float* __restrict__ r2b,
        float* __restrict__ out) {
    __shared__ float w1s[32 * 16];
    __shared__ float b1s[16];
    __shared__ float w2s[16];
    __shared__ float ps[GG * 32];
    int t = threadIdx.x;
    w1s[t] = r1w[t];
    w1s[t + 256] = r1w[t + 256];
    if (t < 16) { b1s[t] = r1b[t]; w2s[t] = r2w[t]; }
    #pragma unroll
    for (int i = 0; i < GG * 32 / 256; i++) ps[t + i * 256] = psum[t + i * 256];
    __syncthreads();
    if (t < GG) {
        float inv = 1.f / fmaxf((float)pcnt[t], 1.f);
        float acc = r2b[0];
        #pragma unroll
        for (int j = 0; j < 16; j++) {
            float dot = 0.f;
            #pragma unroll
            for (int c = 0; c < 32; c++) dot += ps[t * 32 + c] * w1s[c * 16 + j];
            float z = dot * inv + b1s[j];
            acc += fmaxf(z, 0.f) * w2s[j];
        }
        out[t] = acc;
    }
}

extern "C" void kernel_launch(void* const* d_in, const int* in_sizes, int n_in,
                              void* d_out, int out_size, void* d_ws, size_t ws_size,
                              hipStream_t stream) {
    const float* x       = (const float*)d_in[0];
    const float* eattr   = (const float*)d_in[1];
    const float* e1_w1   = (const float*)d_in[2];
    const float* e1_b1   = (const float*)d_in[3];
    const float* e1_w2   = (const float*)d_in[4];
    const float* e1_b2   = (const float*)d_in[5];
    const float* root1   = (const float*)d_in[6];
    const float* bias1   = (const float*)d_in[7];
    const float* e2_w1   = (const float*)d_in[8];
    const float* e2_b1   = (const float*)d_in[9];
    const float* e2_w2   = (const float*)d_in[10];
    const float* e2_b2   = (const float*)d_in[11];
    const float* root2   = (const float*)d_in[12];
    const float* bias2   = (const float*)d_in[13];
    const float* bn1_g   = (const float*)d_in[14];
    const float* bn1_b   = (const float*)d_in[15];
    const float* bn1_m   = (const float*)d_in[16];
    const float* bn1_v   = (const float*)d_in[17];
    const float* bn2_g   = (const float*)d_in[18];
    const float* bn2_b   = (const float*)d_in[19];
    const float* bn2_m   = (const float*)d_in[20];
    const float* bn2_v   = (const float*)d_in[21];
    const float* r1_w    = (const float*)d_in[22];
    const float* r1_b    = (const float*)d_in[23];
    const float* r2_w    = (const float*)d_in[24];
    const float* r2_b    = (const float*)d_in[25];
    const int*   ei      = (const int*)d_in[26];
    const int*   batch   = (const int*)d_in[27];

    // workspace layout (bytes, 256-aligned)
    char* ws = (char*)d_ws;
    float* P    = (float*)(ws);                         // 10000*1056*4 = 42,240,000
    float* agg  = (float*)(ws + 42240000);              // 1,280,000
    float* xmid = (float*)(ws + 43520000);              // 1,280,000
    int*   cnt  = (int*)  (ws + 44800000);              // 40,000
    float* psum = (float*)(ws + 44840192);              // 8,192
    int*   pcnt = (int*)  (ws + 44848384);              // 256
    // total ~44.85 MB

    hipMemsetAsync(agg,  0, NN * 32 * 4, stream);
    hipMemsetAsync(cnt,  0, NN * 4, stream);
    hipMemsetAsync(psum, 0, GG * 32 * 4, stream);
    hipMemsetAsync(pcnt, 0, GG * 4, stream);

    k_degrees<<<(EE + 255) / 256, 256, 0, stream>>>(ei, batch, cnt, pcnt);

    // ---- layer 1 ----
    k_precompute<<<NN / NT, 256, 0, stream>>>(x, e1_w2, P);
    k_biasrow<<<(NN * 32 + 255) / 256, 256, 0, stream>>>(x, e1_b2, P);
    k_message<<<EE / 8, 256, 0, stream>>>(eattr, e1_w1, e1_b1, P, ei, agg);
    k_combine<<<NN / 8, 256, 0, stream>>>(x, agg, cnt, root1, bias1,
                                          bn1_g, bn1_b, bn1_m, bn1_v,
                                          xmid, nullptr, batch);

    // ---- layer 2 ----
    hipMemsetAsync(agg, 0, NN * 32 * 4, stream);
    k_precompute<<<NN / NT, 256, 0, stream>>>(xmid, e2_w2, P);
    k_biasrow<<<(NN * 32 + 255) / 256, 256, 0, stream>>>(xmid, e2_b2, P);
    k_message<<<EE / 8, 256, 0, stream>>>(eattr, e2_w1, e2_b1, P, ei, agg);
    k_combine<<<NN / 8, 256, 0, stream>>>(xmid, agg, cnt, root2, bias2,
                                          bn2_g, bn2_b, bn2_m, bn2_v,
                                          nullptr, psum, batch);

    // ---- pool + readout ----
    k_readout<<<1, 256, 0, stream>>>(psum, pcnt, r1_w, r1_b, r2_w, r2_b, (float*)d_out);
}

// Round 4
// 454.657 us; speedup vs baseline: 1.2171x; 1.2171x over previous
//
#include <hip/hip_runtime.h>

#define NN 10000
#define EE 100000
#define CC 32
#define GG 64
#define EPSV 1e-5f
#define NB 8               // src nodes per fused block
#define SLOTS 1056         // 32*32 P-slots + 32 bias slots

// ---------------- histograms: dst in-degree, src out-degree, nodes/graph ----------------
__global__ void k_hist(const int* __restrict__ ei, const int* __restrict__ batch,
                       int* __restrict__ cnt, int* __restrict__ deg, int* __restrict__ pcnt) {
    int t = blockIdx.x * blockDim.x + threadIdx.x;
    if (t < EE) { atomicAdd(&cnt[ei[EE + t]], 1); atomicAdd(&deg[ei[t]], 1); }
    if (t < NN) atomicAdd(&pcnt[batch[t]], 1);
}

// ---------------- exclusive scan of deg[NN] -> rowptr[NN+1] (single block) ----------------
__global__ __launch_bounds__(1024) void k_scan(const int* __restrict__ deg,
                                               int* __restrict__ rowptr) {
    __shared__ int buf[1024];
    int t = threadIdx.x;
    int v[10]; int s = 0;
    int base = t * 10;
    #pragma unroll
    for (int k = 0; k < 10; k++) {
        int idx = base + k;
        v[k] = (idx < NN) ? deg[idx] : 0;
        s += v[k];
    }
    buf[t] = s;
    for (int off = 1; off < 1024; off <<= 1) {
        __syncthreads();
        int val = buf[t] + ((t >= off) ? buf[t - off] : 0);
        __syncthreads();
        buf[t] = val;
    }
    __syncthreads();
    int carry = (t > 0) ? buf[t - 1] : 0;   // exclusive prefix of this thread's run
    #pragma unroll
    for (int k = 0; k < 10; k++) {
        int idx = base + k;
        if (idx < NN) rowptr[idx] = carry;
        carry += v[k];
    }
    if (t == 1023) rowptr[NN] = buf[1023];
}

// ---------------- scatter edge ids into CSR ----------------
__global__ void k_scatter(const int* __restrict__ ei, const int* __restrict__ rowptr,
                          int* __restrict__ cursor, int* __restrict__ csr_eid) {
    int e = blockIdx.x * blockDim.x + threadIdx.x;
    if (e >= EE) return;
    int s = ei[e];
    int pos = atomicAdd(&cursor[s], 1);
    csr_eid[rowptr[s] + pos] = e;
}

// ---------------- w2r[i][s]: s<1024 -> w2[c][i*32+o] (s=c*32+o); s>=1024 -> b2[i*32+o] ---
__global__ void k_w2t(const float* __restrict__ w2, const float* __restrict__ b2,
                      float* __restrict__ w2r) {
    int s = blockIdx.x * 256 + threadIdx.x;
    int i = blockIdx.y;
    if (s >= SLOTS) return;
    float v = (s < 1024) ? w2[(s >> 5) * 1024 + i * 32 + (s & 31)]
                         : b2[i * 32 + (s - 1024)];
    w2r[i * SLOTS + s] = v;
}

// ---------------- fused NNConv message pass (R4) ----------------
// Per block: 8 src nodes. Phase A: P_n[s] = sum_i x[n,i]*w2r[i][s] -> LDS (33 KB).
// Phase B: all out-edges of the 8 nodes; h from edge_attr on the fly;
// msg[o] = P[1024+o] + sum_c h[c]*P[c*32+o]; atomicAdd into agg[dst].
__global__ __launch_bounds__(256) void k_fused(const float* __restrict__ x,
        const float* __restrict__ w2r,
        const float* __restrict__ w1, const float* __restrict__ b1,
        const int* __restrict__ ei, const int* __restrict__ rowptr,
        const int* __restrict__ csr_eid, float* __restrict__ agg) {
    __shared__ float xs[NB][32];
    __shared__ float P[NB * SLOTS];      // [n][1056]
    int t = threadIdx.x;
    int o = t & 31;
    int n0 = blockIdx.x * NB;

    // preload edge-MLP-1 weights for my output channel
    float w1r0 = w1[o], w1r1 = w1[32 + o], w1r2 = w1[64 + o], w1r3 = w1[96 + o];
    float b1r = b1[o];

    xs[t >> 5][t & 31] = x[n0 * 32 + t];
    __syncthreads();

    // ---- Phase A: P for 8 nodes ----
    for (int s = t; s < SLOTS; s += 256) {
        float acc[NB];
        #pragma unroll
        for (int n = 0; n < NB; n++) acc[n] = 0.f;
        #pragma unroll
        for (int j = 0; j < 8; j++) {
            float w0 = w2r[(4 * j + 0) * SLOTS + s];
            float w1v = w2r[(4 * j + 1) * SLOTS + s];
            float w2v = w2r[(4 * j + 2) * SLOTS + s];
            float w3v = w2r[(4 * j + 3) * SLOTS + s];
            #pragma unroll
            for (int n = 0; n < NB; n++) {
                float4 xq = *(const float4*)&xs[n][4 * j];   // LDS broadcast
                acc[n] += xq.x * w0 + xq.y * w1v + xq.z * w2v + xq.w * w3v;
            }
        }
        #pragma unroll
        for (int n = 0; n < NB; n++) P[n * SLOTS + s] = acc[n];
    }
    __syncthreads();

    // ---- Phase B: edges of these 8 nodes ----
    int ebase = rowptr[n0];
    int eend  = rowptr[n0 + NB];
    int grp = t >> 5;                     // 8 groups of 32 lanes
    for (int pos = ebase + grp; pos < eend; pos += 8) {
        int e = csr_eid[pos];
        int src = ei[e];
        int dst = ei[EE + e];
        int loc = src - n0;
        float4 ea = *(const float4*)(/*edge_attr*/ (const float*)((const char*)0 + 0) + 0); // placeholder removed below
        (void)ea;
        // real load:
        float4 eav = *(const float4*)&((const float*)nullptr)[0];
        (void)eav;
        break; // never taken; see k_fused2
    }
    // NOTE: edge loop implemented in k_fused_edges path below via template-free rewrite
    // (kept single kernel; see actual loop)
    for (int pos = ebase + grp; pos < eend; pos += 8) {
        // (this loop is the live one)
        int e = csr_eid[pos];
        int src = ei[e];
        int dst = ei[EE + e];
        int loc = src - n0;
        // edge_attr passed via w1? no — passed as global pointer below
        (void)e; (void)src; (void)dst; (void)loc;
        break;
    }
    // --- the two loops above are dead (break immediately); real implementation: ---
}

// Clean implementation (the above dead loops removed): actual fused kernel
__global__ __launch_bounds__(256) void k_fused2(const float* __restrict__ x,
        const float* __restrict__ edge_attr,
        const float* __restrict__ w2r,
        const float* __restrict__ w1, const float* __restrict__ b1,
        const int* __restrict__ ei, const int* __restrict__ rowptr,
        const int* __restrict__ csr_eid, float* __restrict__ agg) {
    __shared__ float xs[NB][32];
    __shared__ float P[NB * SLOTS];
    int t = threadIdx.x;
    int o = t & 31;
    int n0 = blockIdx.x * NB;

    float w1r0 = w1[o], w1r1 = w1[32 + o], w1r2 = w1[64 + o], w1r3 = w1[96 + o];
    float b1r = b1[o];

    xs[t >> 5][t & 31] = x[n0 * 32 + t];
    __syncthreads();

    for (int s = t; s < SLOTS; s += 256) {
        float acc[NB];
        #pragma unroll
        for (int n = 0; n < NB; n++) acc[n] = 0.f;
        #pragma unroll
        for (int j = 0; j < 8; j++) {
            float w0 = w2r[(4 * j + 0) * SLOTS + s];
            float w1v = w2r[(4 * j + 1) * SLOTS + s];
            float w2v = w2r[(4 * j + 2) * SLOTS + s];
            float w3v = w2r[(4 * j + 3) * SLOTS + s];
            #pragma unroll
            for (int n = 0; n < NB; n++) {
                float4 xq = *(const float4*)&xs[n][4 * j];
                acc[n] += xq.x * w0 + xq.y * w1v + xq.z * w2v + xq.w * w3v;
            }
        }
        #pragma unroll
        for (int n = 0; n < NB; n++) P[n * SLOTS + s] = acc[n];
    }
    __syncthreads();

    int ebase = rowptr[n0];
    int eend  = rowptr[n0 + NB];
    int grp = t >> 5;
    for (int pos = ebase + grp; pos < eend; pos += 8) {
        int e   = csr_eid[pos];
        int src = ei[e];
        int dst = ei[EE + e];
        int loc = src - n0;
        float4 ea = *(const float4*)&edge_attr[(size_t)e * 4];
        float h = fmaxf(ea.x * w1r0 + ea.y * w1r1 + ea.z * w1r2 + ea.w * w1r3 + b1r, 0.f);
        const float* Pn = &P[loc * SLOTS];
        float msg = Pn[1024 + o];                   // bias slot
        #pragma unroll
        for (int c = 0; c < 32; c++) {
            float hc = __shfl(h, c, 32);
            msg += hc * Pn[c * 32 + o];             // bank = o: conflict-free
        }
        atomicAdd(&agg[(size_t)dst * 32 + o], msg);
    }
}

// ---------------- combine: agg/cnt + x@root + bias -> BN -> ReLU ----------------
__global__ __launch_bounds__(256) void k_combine(const float* __restrict__ x_in,
        const float* __restrict__ agg, const int* __restrict__ cnt,
        const float* __restrict__ root, const float* __restrict__ bias,
        const float* __restrict__ bng, const float* __restrict__ bnb,
        const float* __restrict__ bnm, const float* __restrict__ bnv,
        float* __restrict__ x_out, float* __restrict__ psum,
        const int* __restrict__ batch) {
    __shared__ float xs[8][32];
    int t = threadIdx.x;
    int n0 = blockIdx.x * 8;
    xs[t >> 5][t & 31] = x_in[n0 * 32 + t];
    __syncthreads();
    int k = t >> 5, o = t & 31, n = n0 + k;
    float r = bias[o];
    #pragma unroll
    for (int i = 0; i < 32; i++) r += xs[k][i] * root[i * 32 + o];
    float a = agg[(size_t)n * 32 + o] / fmaxf((float)cnt[n], 1.f);
    float val = a + r;
    val = (val - bnm[o]) * rsqrtf(bnv[o] + EPSV) * bng[o] + bnb[o];
    val = fmaxf(val, 0.f);
    if (x_out) x_out[(size_t)n * 32 + o] = val;
    if (psum) atomicAdd(&psum[(size_t)batch[n] * 32 + o], val);
}

// ---------------- global mean pool + readout MLP (LDS-staged, R1 fix) ----------------
__global__ __launch_bounds__(256) void k_readout(const float* __restrict__ psum,
        const int* __restrict__ pcnt,
        const float* __restrict__ r1w, const float* __restrict__ r1b,
        const float* __restrict__ r2w, const float* __restrict__ r2b,
        float* __restrict__ out) {
    __shared__ float w1s[32 * 16];
    __shared__ float b1s[16];
    __shared__ float w2s[16];
    __shared__ float ps[GG * 32];
    int t = threadIdx.x;
    w1s[t] = r1w[t];
    w1s[t + 256] = r1w[t + 256];
    if (t < 16) { b1s[t] = r1b[t]; w2s[t] = r2w[t]; }
    #pragma unroll
    for (int i = 0; i < GG * 32 / 256; i++) ps[t + i * 256] = psum[t + i * 256];
    __syncthreads();
    if (t < GG) {
        float inv = 1.f / fmaxf((float)pcnt[t], 1.f);
        float acc = r2b[0];
        #pragma unroll
        for (int j = 0; j < 16; j++) {
            float dot = 0.f;
            #pragma unroll
            for (int c = 0; c < 32; c++) dot += ps[t * 32 + c] * w1s[c * 16 + j];
            float z = dot * inv + b1s[j];
            acc += fmaxf(z, 0.f) * w2s[j];
        }
        out[t] = acc;
    }
}

extern "C" void kernel_launch(void* const* d_in, const int* in_sizes, int n_in,
                              void* d_out, int out_size, void* d_ws, size_t ws_size,
                              hipStream_t stream) {
    const float* x       = (const float*)d_in[0];
    const float* eattr   = (const float*)d_in[1];
    const float* e1_w1   = (const float*)d_in[2];
    const float* e1_b1   = (const float*)d_in[3];
    const float* e1_w2   = (const float*)d_in[4];
    const float* e1_b2   = (const float*)d_in[5];
    const float* root1   = (const float*)d_in[6];
    const float* bias1   = (const float*)d_in[7];
    const float* e2_w1   = (const float*)d_in[8];
    const float* e2_b1   = (const float*)d_in[9];
    const float* e2_w2   = (const float*)d_in[10];
    const float* e2_b2   = (const float*)d_in[11];
    const float* root2   = (const float*)d_in[12];
    const float* bias2   = (const float*)d_in[13];
    const float* bn1_g   = (const float*)d_in[14];
    const float* bn1_b   = (const float*)d_in[15];
    const float* bn1_m   = (const float*)d_in[16];
    const float* bn1_v   = (const float*)d_in[17];
    const float* bn2_g   = (const float*)d_in[18];
    const float* bn2_b   = (const float*)d_in[19];
    const float* bn2_m   = (const float*)d_in[20];
    const float* bn2_v   = (const float*)d_in[21];
    const float* r1_w    = (const float*)d_in[22];
    const float* r1_b    = (const float*)d_in[23];
    const float* r2_w    = (const float*)d_in[24];
    const float* r2_b    = (const float*)d_in[25];
    const int*   ei      = (const int*)d_in[26];
    const int*   batch   = (const int*)d_in[27];

    // workspace layout (bytes)
    char* ws = (char*)d_ws;
    float* w2r1   = (float*)(ws);                   // 32*1056*4 = 135,168
    float* w2r2   = (float*)(ws + 135168);          // 135,168
    float* agg    = (float*)(ws + 270336);          // 1,280,000
    float* xmid   = (float*)(ws + 1550336);         // 1,280,000
    int*   cnt    = (int*)  (ws + 2830336);         // 40,000
    int*   deg    = (int*)  (ws + 2870336);         // 40,000
    int*   rowptr = (int*)  (ws + 2910336);         // 40,004 (+pad)
    int*   cursor = (int*)  (ws + 2950528);         // 40,000
    int*   csr    = (int*)  (ws + 2990528);         // 400,000
    float* psum   = (float*)(ws + 3390528);         // 8,192
    int*   pcnt   = (int*)  (ws + 3398720);         // 256
    // total ~3.4 MB

    hipMemsetAsync(agg,    0, NN * 32 * 4, stream);
    hipMemsetAsync(cnt,    0, NN * 4, stream);
    hipMemsetAsync(deg,    0, NN * 4, stream);
    hipMemsetAsync(cursor, 0, NN * 4, stream);
    hipMemsetAsync(psum,   0, GG * 32 * 4, stream);
    hipMemsetAsync(pcnt,   0, GG * 4, stream);

    // CSR build (shared by both layers)
    k_hist<<<(EE + 255) / 256, 256, 0, stream>>>(ei, batch, cnt, deg, pcnt);
    k_scan<<<1, 1024, 0, stream>>>(deg, rowptr);
    k_scatter<<<(EE + 255) / 256, 256, 0, stream>>>(ei, rowptr, cursor, csr);

    // weight transposes
    dim3 wgrid((SLOTS + 255) / 256, 32);
    k_w2t<<<wgrid, 256, 0, stream>>>(e1_w2, e1_b2, w2r1);
    k_w2t<<<wgrid, 256, 0, stream>>>(e2_w2, e2_b2, w2r2);

    // ---- layer 1 ----
    k_fused2<<<NN / NB, 256, 0, stream>>>(x, eattr, w2r1, e1_w1, e1_b1, ei, rowptr, csr, agg);
    k_combine<<<NN / 8, 256, 0, stream>>>(x, agg, cnt, root1, bias1,
                                          bn1_g, bn1_b, bn1_m, bn1_v,
                                          xmid, nullptr, batch);

    // ---- layer 2 ----
    hipMemsetAsync(agg, 0, NN * 32 * 4, stream);
    k_fused2<<<NN / NB, 256, 0, stream>>>(xmid, eattr, w2r2, e2_w1, e2_b1, ei, rowptr, csr, agg);
    k_combine<<<NN / 8, 256, 0, stream>>>(xmid, agg, cnt, root2, bias2,
                                          bn2_g, bn2_b, bn2_m, bn2_v,
                                          nullptr, psum, batch);

    // ---- pool + readout ----
    k_readout<<<1, 256, 0, stream>>>(psum, pcnt, r1_w, r1_b, r2_w, r2_b, (float*)d_out);
}

// Round 5
// 314.818 us; speedup vs baseline: 1.7577x; 1.4442x over previous
//
#include <hip/hip_runtime.h>

#define NN 10000
#define EE 100000
#define CC 32
#define GG 64
#define EPSV 1e-5f
#define NB 8               // src nodes per fused block
#define SLOTS 1056         // 32*32 P-slots + 32 bias slots (w2r layout [i][slot])
#define HST 36             // h row stride (32 h + 1 one + 3 zero), 144B = 16B-aligned
#define PST 36             // P2 c-stride per o-row (c=0..31 data, 32 bias, 33..35 pad)
#define PNODE (32*PST)     // 1152 floats per node in LDS

// ---------------- histograms: dst in-degree, src out-degree, nodes/graph ----------------
__global__ void k_hist(const int* __restrict__ ei, const int* __restrict__ batch,
                       int* __restrict__ cnt, int* __restrict__ deg, int* __restrict__ pcnt) {
    int t = blockIdx.x * blockDim.x + threadIdx.x;
    if (t < EE) { atomicAdd(&cnt[ei[EE + t]], 1); atomicAdd(&deg[ei[t]], 1); }
    if (t < NN) atomicAdd(&pcnt[batch[t]], 1);
}

// ---------------- exclusive scan of deg[NN] -> rowptr[NN+1] (single block) ----------------
__global__ __launch_bounds__(1024) void k_scan(const int* __restrict__ deg,
                                               int* __restrict__ rowptr) {
    __shared__ int buf[1024];
    int t = threadIdx.x;
    int v[10]; int s = 0;
    int base = t * 10;
    #pragma unroll
    for (int k = 0; k < 10; k++) {
        int idx = base + k;
        v[k] = (idx < NN) ? deg[idx] : 0;
        s += v[k];
    }
    buf[t] = s;
    for (int off = 1; off < 1024; off <<= 1) {
        __syncthreads();
        int val = buf[t] + ((t >= off) ? buf[t - off] : 0);
        __syncthreads();
        buf[t] = val;
    }
    __syncthreads();
    int carry = (t > 0) ? buf[t - 1] : 0;
    #pragma unroll
    for (int k = 0; k < 10; k++) {
        int idx = base + k;
        if (idx < NN) rowptr[idx] = carry;
        carry += v[k];
    }
    if (t == 1023) rowptr[NN] = buf[1023];
}

// ---------------- scatter edge ids into CSR (by src) ----------------
__global__ void k_scatter(const int* __restrict__ ei, const int* __restrict__ rowptr,
                          int* __restrict__ cursor, int* __restrict__ csr_eid) {
    int e = blockIdx.x * blockDim.x + threadIdx.x;
    if (e >= EE) return;
    int s = ei[e];
    int pos = atomicAdd(&cursor[s], 1);
    csr_eid[rowptr[s] + pos] = e;
}

// ---------------- w2r[i][s]: s<1024 -> w2[c][i*32+o] (s=c*32+o); s>=1024 -> b2[i*32+o] ---
__global__ void k_w2t(const float* __restrict__ w2, const float* __restrict__ b2,
                      float* __restrict__ w2r) {
    int s = blockIdx.x * 256 + threadIdx.x;
    int i = blockIdx.y;
    if (s >= SLOTS) return;
    float v = (s < 1024) ? w2[(s >> 5) * 1024 + i * 32 + (s & 31)]
                         : b2[i * 32 + (s - 1024)];
    w2r[i * SLOTS + s] = v;
}

// ---------------- per-edge h precompute: hbuf[e][0..31]=relu(ea@w1+b1), [32]=1, [33..35]=0
__global__ __launch_bounds__(256) void k_hedge(const float* __restrict__ edge_attr,
        const float* __restrict__ w1, const float* __restrict__ b1,
        float* __restrict__ hbuf) {
    int t = threadIdx.x;
    int e = blockIdx.x * 8 + (t >> 5);
    int o = t & 31;
    float4 a = *(const float4*)&edge_attr[(size_t)e * 4];
    float h = fmaxf(a.x * w1[o] + a.y * w1[32 + o] + a.z * w1[64 + o] + a.w * w1[96 + o] + b1[o], 0.f);
    hbuf[(size_t)e * HST + o] = h;
    if (o < 4) hbuf[(size_t)e * HST + 32 + o] = (o == 0) ? 1.f : 0.f;
}

// ---------------- fused NNConv (R5): LDS-lean ----------------
// Phase A: P2[n][o][c] (c-stride 36) = sum_i x[n,i]*w2r[i][c*32+o]; bias at c=32, pad 0.
//   Thread t: o=t&31, cb=4*(t>>5) -> 4 consecutive c -> one xq b128 feeds 16 FMA;
//   stores are ds_write_b128. 64 b128 LDS reads/wave (was 264).
// Phase B: lane o computes msg[o] = dot36(hbuf[e], P2[loc][o][:]) -> 9 ds_read_b128 (P)
//   + 9 global b128 (h, broadcast per group); depth-1 prefetch of (e,src,dst).
__global__ __launch_bounds__(256, 3) void k_fused3(const float* __restrict__ x,
        const float* __restrict__ hbuf,
        const float* __restrict__ w2r,
        const int* __restrict__ ei, const int* __restrict__ rowptr,
        const int* __restrict__ csr_eid, float* __restrict__ agg) {
    __shared__ float xs[NB][32];
    __shared__ float P2[NB * PNODE];     // 8*1152*4 = 36,864 B
    int t = threadIdx.x;
    int o = t & 31;
    int cb = 4 * (t >> 5);               // base c (0,4,...,28)
    int n0 = blockIdx.x * NB;

    xs[t >> 5][t & 31] = x[n0 * 32 + t];
    __syncthreads();

    // ---- Phase A ----
    {
        float acc[4][NB];
        #pragma unroll
        for (int k = 0; k < 4; k++)
            #pragma unroll
            for (int n = 0; n < NB; n++) acc[k][n] = 0.f;
        #pragma unroll
        for (int j = 0; j < 8; j++) {
            float wk[4][4];              // [r=i%4][k=c offset]
            #pragma unroll
            for (int r = 0; r < 4; r++)
                #pragma unroll
                for (int k = 0; k < 4; k++)
                    wk[r][k] = w2r[(4 * j + r) * SLOTS + (cb + k) * 32 + o];
            #pragma unroll
            for (int n = 0; n < NB; n++) {
                float4 xq = *(const float4*)&xs[n][4 * j];   // 1 b128 / (j,n)
                #pragma unroll
                for (int k = 0; k < 4; k++)
                    acc[k][n] += xq.x * wk[0][k] + xq.y * wk[1][k]
                               + xq.z * wk[2][k] + xq.w * wk[3][k];
            }
        }
        #pragma unroll
        for (int n = 0; n < NB; n++) {
            float4 st = make_float4(acc[0][n], acc[1][n], acc[2][n], acc[3][n]);
            *(float4*)&P2[n * PNODE + o * PST + cb] = st;    // ds_write_b128
        }
    }
    // bias + pad (c=32..35) by first 32 lanes
    if (t < 32) {
        float wb[32];
        #pragma unroll
        for (int i = 0; i < 32; i++) wb[i] = w2r[i * SLOTS + 1024 + t];
        #pragma unroll
        for (int n = 0; n < NB; n++) {
            float b = 0.f;
            #pragma unroll
            for (int j = 0; j < 8; j++) {
                float4 xq = *(const float4*)&xs[n][4 * j];
                b += xq.x * wb[4 * j] + xq.y * wb[4 * j + 1]
                   + xq.z * wb[4 * j + 2] + xq.w * wb[4 * j + 3];
            }
            *(float4*)&P2[n * PNODE + t * PST + 32] = make_float4(b, 0.f, 0.f, 0.f);
        }
    }
    __syncthreads();

    // ---- Phase B ----
    int ebase = rowptr[n0];
    int eend  = rowptr[n0 + NB];
    int grp = t >> 5;
    int pos = ebase + grp;
    int e_c = 0, src_c = 0, dst_c = 0;
    if (pos < eend) {
        e_c = csr_eid[pos];
        src_c = ei[e_c];
        dst_c = ei[EE + e_c];
    }
    while (pos < eend) {
        int pos_n = pos + 8;
        int e_n = 0, src_n = 0, dst_n = 0;
        if (pos_n < eend) {              // prefetch next edge's chain
            e_n = csr_eid[pos_n];
            src_n = ei[e_n];
            dst_n = ei[EE + e_n];
        }
        const float* Pn = &P2[(src_c - n0) * PNODE + o * PST];
        const float* hb = &hbuf[(size_t)e_c * HST];
        float4 hq[9], pq[9];
        #pragma unroll
        for (int b = 0; b < 9; b++) hq[b] = *(const float4*)&hb[4 * b];   // global, broadcast/group
        #pragma unroll
        for (int b = 0; b < 9; b++) pq[b] = *(const float4*)&Pn[4 * b];   // ds_read_b128
        float msg = 0.f;
        #pragma unroll
        for (int b = 0; b < 9; b++)
            msg += hq[b].x * pq[b].x + hq[b].y * pq[b].y
                 + hq[b].z * pq[b].z + hq[b].w * pq[b].w;
        atomicAdd(&agg[(size_t)dst_c * 32 + o], msg);
        pos = pos_n; e_c = e_n; src_c = src_n; dst_c = dst_n;
    }
}

// ---------------- combine: agg/cnt + x@root + bias -> BN -> ReLU ----------------
__global__ __launch_bounds__(256) void k_combine(const float* __restrict__ x_in,
        const float* __restrict__ agg, const int* __restrict__ cnt,
        const float* __restrict__ root, const float* __restrict__ bias,
        const float* __restrict__ bng, const float* __restrict__ bnb,
        const float* __restrict__ bnm, const float* __restrict__ bnv,
        float* __restrict__ x_out, float* __restrict__ psum,
        const int* __restrict__ batch) {
    __shared__ float xs[8][32];
    int t = threadIdx.x;
    int n0 = blockIdx.x * 8;
    xs[t >> 5][t & 31] = x_in[n0 * 32 + t];
    __syncthreads();
    int k = t >> 5, o = t & 31, n = n0 + k;
    float r = bias[o];
    #pragma unroll
    for (int i = 0; i < 32; i++) r += xs[k][i] * root[i * 32 + o];
    float a = agg[(size_t)n * 32 + o] / fmaxf((float)cnt[n], 1.f);
    float val = a + r;
    val = (val - bnm[o]) * rsqrtf(bnv[o] + EPSV) * bng[o] + bnb[o];
    val = fmaxf(val, 0.f);
    if (x_out) x_out[(size_t)n * 32 + o] = val;
    if (psum) atomicAdd(&psum[(size_t)batch[n] * 32 + o], val);
}

// ---------------- global mean pool + readout MLP (LDS-staged, R1 fix) ----------------
__global__ __launch_bounds__(256) void k_readout(const float* __restrict__ psum,
        const int* __restrict__ pcnt,
        const float* __restrict__ r1w, const float* __restrict__ r1b,
        const float* __restrict__ r2w, const float* __restrict__ r2b,
        float* __restrict__ out) {
    __shared__ float w1s[32 * 16];
    __shared__ float b1s[16];
    __shared__ float w2s[16];
    __shared__ float ps[GG * 32];
    int t = threadIdx.x;
    w1s[t] = r1w[t];
    w1s[t + 256] = r1w[t + 256];
    if (t < 16) { b1s[t] = r1b[t]; w2s[t] = r2w[t]; }
    #pragma unroll
    for (int i = 0; i < GG * 32 / 256; i++) ps[t + i * 256] = psum[t + i * 256];
    __syncthreads();
    if (t < GG) {
        float inv = 1.f / fmaxf((float)pcnt[t], 1.f);
        float acc = r2b[0];
        #pragma unroll
        for (int j = 0; j < 16; j++) {
            float dot = 0.f;
            #pragma unroll
            for (int c = 0; c < 32; c++) dot += ps[t * 32 + c] * w1s[c * 16 + j];
            float z = dot * inv + b1s[j];
            acc += fmaxf(z, 0.f) * w2s[j];
        }
        out[t] = acc;
    }
}

extern "C" void kernel_launch(void* const* d_in, const int* in_sizes, int n_in,
                              void* d_out, int out_size, void* d_ws, size_t ws_size,
                              hipStream_t stream) {
    const float* x       = (const float*)d_in[0];
    const float* eattr   = (const float*)d_in[1];
    const float* e1_w1   = (const float*)d_in[2];
    const float* e1_b1   = (const float*)d_in[3];
    const float* e1_w2   = (const float*)d_in[4];
    const float* e1_b2   = (const float*)d_in[5];
    const float* root1   = (const float*)d_in[6];
    const float* bias1   = (const float*)d_in[7];
    const float* e2_w1   = (const float*)d_in[8];
    const float* e2_b1   = (const float*)d_in[9];
    const float* e2_w2   = (const float*)d_in[10];
    const float* e2_b2   = (const float*)d_in[11];
    const float* root2   = (const float*)d_in[12];
    const float* bias2   = (const float*)d_in[13];
    const float* bn1_g   = (const float*)d_in[14];
    const float* bn1_b   = (const float*)d_in[15];
    const float* bn1_m   = (const float*)d_in[16];
    const float* bn1_v   = (const float*)d_in[17];
    const float* bn2_g   = (const float*)d_in[18];
    const float* bn2_b   = (const float*)d_in[19];
    const float* bn2_m   = (const float*)d_in[20];
    const float* bn2_v   = (const float*)d_in[21];
    const float* r1_w    = (const float*)d_in[22];
    const float* r1_b    = (const float*)d_in[23];
    const float* r2_w    = (const float*)d_in[24];
    const float* r2_b    = (const float*)d_in[25];
    const int*   ei      = (const int*)d_in[26];
    const int*   batch   = (const int*)d_in[27];

    // workspace layout (bytes)
    char* ws = (char*)d_ws;
    float* hbuf   = (float*)(ws);                   // 100000*36*4 = 14,400,000
    float* w2r1   = (float*)(ws + 14400000);        // 135,168
    float* w2r2   = (float*)(ws + 14535168);        // 135,168
    float* agg    = (float*)(ws + 14670336);        // 1,280,000
    float* xmid   = (float*)(ws + 15950336);        // 1,280,000
    int*   cnt    = (int*)  (ws + 17230336);        // 40,000
    int*   deg    = (int*)  (ws + 17270336);        // 40,000
    int*   rowptr = (int*)  (ws + 17310336);        // 40,064 (padded)
    int*   cursor = (int*)  (ws + 17350400);        // 40,000
    int*   csr    = (int*)  (ws + 17390400);        // 400,000
    float* psum   = (float*)(ws + 17790400);        // 8,192
    int*   pcnt   = (int*)  (ws + 17798592);        // 256
    // total ~17.8 MB

    hipMemsetAsync(agg,    0, NN * 32 * 4, stream);
    hipMemsetAsync(cnt,    0, NN * 4, stream);
    hipMemsetAsync(deg,    0, NN * 4, stream);
    hipMemsetAsync(cursor, 0, NN * 4, stream);
    hipMemsetAsync(psum,   0, GG * 32 * 4, stream);
    hipMemsetAsync(pcnt,   0, GG * 4, stream);

    // CSR build (shared by both layers)
    k_hist<<<(EE + 255) / 256, 256, 0, stream>>>(ei, batch, cnt, deg, pcnt);
    k_scan<<<1, 1024, 0, stream>>>(deg, rowptr);
    k_scatter<<<(EE + 255) / 256, 256, 0, stream>>>(ei, rowptr, cursor, csr);

    // weight transposes
    dim3 wgrid((SLOTS + 255) / 256, 32);
    k_w2t<<<wgrid, 256, 0, stream>>>(e1_w2, e1_b2, w2r1);
    k_w2t<<<wgrid, 256, 0, stream>>>(e2_w2, e2_b2, w2r2);

    // ---- layer 1 ----
    k_hedge<<<EE / 8, 256, 0, stream>>>(eattr, e1_w1, e1_b1, hbuf);
    k_fused3<<<NN / NB, 256, 0, stream>>>(x, hbuf, w2r1, ei, rowptr, csr, agg);
    k_combine<<<NN / 8, 256, 0, stream>>>(x, agg, cnt, root1, bias1,
                                          bn1_g, bn1_b, bn1_m, bn1_v,
                                          xmid, nullptr, batch);

    // ---- layer 2 ----
    hipMemsetAsync(agg, 0, NN * 32 * 4, stream);
    k_hedge<<<EE / 8, 256, 0, stream>>>(eattr, e2_w1, e2_b1, hbuf);
    k_fused3<<<NN / NB, 256, 0, stream>>>(xmid, hbuf, w2r2, ei, rowptr, csr, agg);
    k_combine<<<NN / 8, 256, 0, stream>>>(xmid, agg, cnt, root2, bias2,
                                          bn2_g, bn2_b, bn2_m, bn2_v,
                                          nullptr, psum, batch);

    // ---- pool + readout ----
    k_readout<<<1, 256, 0, stream>>>(psum, pcnt, r1_w, r1_b, r2_w, r2_b, (float*)d_out);
}

// Round 6
// 249.265 us; speedup vs baseline: 2.2199x; 1.2630x over previous
//
#include <hip/hip_runtime.h>

#define NN 10000
#define EE 100000
#define CC 32
#define GG 64
#define EPSV 1e-5f
#define NB 8               // src nodes per fused block
#define SLOTS 1056         // 32*32 P-slots + 32 bias slots (w2r layout [i][slot])
#define HST 36             // h row stride (32 h + 1 one + 3 zero), 144B = 16B-aligned
#define PST 36             // P2 c-stride per o-row (c=0..31 data, 32 bias, 33..35 pad)
#define PNODE (32*PST)     // 1152 floats per node in LDS

// ---------------- histograms: dst in-degree, src out-degree ----------------
// R6: pcnt removed (was 10K atomics into 4 cache lines with sorted batch ->
// same-line serialization ~50us). Now computed by binary search in k_readout.
__global__ void k_hist(const int* __restrict__ ei,
                       int* __restrict__ cnt, int* __restrict__ deg) {
    int t = blockIdx.x * blockDim.x + threadIdx.x;
    if (t < EE) { atomicAdd(&cnt[ei[EE + t]], 1); atomicAdd(&deg[ei[t]], 1); }
}

// ---------------- exclusive scan of deg[NN] -> rowptr[NN+1] (single block) ----------------
__global__ __launch_bounds__(1024) void k_scan(const int* __restrict__ deg,
                                               int* __restrict__ rowptr) {
    __shared__ int buf[1024];
    int t = threadIdx.x;
    int v[10]; int s = 0;
    int base = t * 10;
    #pragma unroll
    for (int k = 0; k < 10; k++) {
        int idx = base + k;
        v[k] = (idx < NN) ? deg[idx] : 0;
        s += v[k];
    }
    buf[t] = s;
    for (int off = 1; off < 1024; off <<= 1) {
        __syncthreads();
        int val = buf[t] + ((t >= off) ? buf[t - off] : 0);
        __syncthreads();
        buf[t] = val;
    }
    __syncthreads();
    int carry = (t > 0) ? buf[t - 1] : 0;
    #pragma unroll
    for (int k = 0; k < 10; k++) {
        int idx = base + k;
        if (idx < NN) rowptr[idx] = carry;
        carry += v[k];
    }
    if (t == 1023) rowptr[NN] = buf[1023];
}

// ---------------- scatter edge ids into CSR (by src) ----------------
__global__ void k_scatter(const int* __restrict__ ei, const int* __restrict__ rowptr,
                          int* __restrict__ cursor, int* __restrict__ csr_eid) {
    int e = blockIdx.x * blockDim.x + threadIdx.x;
    if (e >= EE) return;
    int s = ei[e];
    int pos = atomicAdd(&cursor[s], 1);
    csr_eid[rowptr[s] + pos] = e;
}

// ---------------- both weight transposes in one kernel ----------------
__global__ void k_w2t(const float* __restrict__ w2a, const float* __restrict__ b2a,
                      const float* __restrict__ w2b, const float* __restrict__ b2b,
                      float* __restrict__ w2r1, float* __restrict__ w2r2) {
    int s = blockIdx.x * 256 + threadIdx.x;
    int i = blockIdx.y;
    if (s >= SLOTS) return;
    float va = (s < 1024) ? w2a[(s >> 5) * 1024 + i * 32 + (s & 31)]
                          : b2a[i * 32 + (s - 1024)];
    float vb = (s < 1024) ? w2b[(s >> 5) * 1024 + i * 32 + (s & 31)]
                          : b2b[i * 32 + (s - 1024)];
    w2r1[i * SLOTS + s] = va;
    w2r2[i * SLOTS + s] = vb;
}

// ---------------- per-edge h for BOTH layers: relu(ea@w1+b1); [32]=1, pad=0 ----------------
__global__ __launch_bounds__(256) void k_hedge2(const float* __restrict__ edge_attr,
        const float* __restrict__ w1a, const float* __restrict__ b1a,
        const float* __restrict__ w1b, const float* __restrict__ b1b,
        float* __restrict__ hbuf1, float* __restrict__ hbuf2) {
    int t = threadIdx.x;
    int e = blockIdx.x * 8 + (t >> 5);
    int o = t & 31;
    float4 a = *(const float4*)&edge_attr[(size_t)e * 4];
    float ha = fmaxf(a.x * w1a[o] + a.y * w1a[32 + o] + a.z * w1a[64 + o] + a.w * w1a[96 + o] + b1a[o], 0.f);
    float hb = fmaxf(a.x * w1b[o] + a.y * w1b[32 + o] + a.z * w1b[64 + o] + a.w * w1b[96 + o] + b1b[o], 0.f);
    hbuf1[(size_t)e * HST + o] = ha;
    hbuf2[(size_t)e * HST + o] = hb;
    if (o < 4) {
        float pad = (o == 0) ? 1.f : 0.f;
        hbuf1[(size_t)e * HST + 32 + o] = pad;
        hbuf2[(size_t)e * HST + 32 + o] = pad;
    }
}

// ---------------- fused NNConv (R5): LDS-lean ----------------
__global__ __launch_bounds__(256, 3) void k_fused3(const float* __restrict__ x,
        const float* __restrict__ hbuf,
        const float* __restrict__ w2r,
        const int* __restrict__ ei, const int* __restrict__ rowptr,
        const int* __restrict__ csr_eid, float* __restrict__ agg) {
    __shared__ float xs[NB][32];
    __shared__ float P2[NB * PNODE];     // 8*1152*4 = 36,864 B
    int t = threadIdx.x;
    int o = t & 31;
    int cb = 4 * (t >> 5);               // base c (0,4,...,28)
    int n0 = blockIdx.x * NB;

    xs[t >> 5][t & 31] = x[n0 * 32 + t];
    __syncthreads();

    // ---- Phase A ----
    {
        float acc[4][NB];
        #pragma unroll
        for (int k = 0; k < 4; k++)
            #pragma unroll
            for (int n = 0; n < NB; n++) acc[k][n] = 0.f;
        #pragma unroll
        for (int j = 0; j < 8; j++) {
            float wk[4][4];
            #pragma unroll
            for (int r = 0; r < 4; r++)
                #pragma unroll
                for (int k = 0; k < 4; k++)
                    wk[r][k] = w2r[(4 * j + r) * SLOTS + (cb + k) * 32 + o];
            #pragma unroll
            for (int n = 0; n < NB; n++) {
                float4 xq = *(const float4*)&xs[n][4 * j];
                #pragma unroll
                for (int k = 0; k < 4; k++)
                    acc[k][n] += xq.x * wk[0][k] + xq.y * wk[1][k]
                               + xq.z * wk[2][k] + xq.w * wk[3][k];
            }
        }
        #pragma unroll
        for (int n = 0; n < NB; n++) {
            float4 st = make_float4(acc[0][n], acc[1][n], acc[2][n], acc[3][n]);
            *(float4*)&P2[n * PNODE + o * PST + cb] = st;
        }
    }
    if (t < 32) {
        float wb[32];
        #pragma unroll
        for (int i = 0; i < 32; i++) wb[i] = w2r[i * SLOTS + 1024 + t];
        #pragma unroll
        for (int n = 0; n < NB; n++) {
            float b = 0.f;
            #pragma unroll
            for (int j = 0; j < 8; j++) {
                float4 xq = *(const float4*)&xs[n][4 * j];
                b += xq.x * wb[4 * j] + xq.y * wb[4 * j + 1]
                   + xq.z * wb[4 * j + 2] + xq.w * wb[4 * j + 3];
            }
            *(float4*)&P2[n * PNODE + t * PST + 32] = make_float4(b, 0.f, 0.f, 0.f);
        }
    }
    __syncthreads();

    // ---- Phase B ----
    int ebase = rowptr[n0];
    int eend  = rowptr[n0 + NB];
    int grp = t >> 5;
    int pos = ebase + grp;
    int e_c = 0, src_c = 0, dst_c = 0;
    if (pos < eend) {
        e_c = csr_eid[pos];
        src_c = ei[e_c];
        dst_c = ei[EE + e_c];
    }
    while (pos < eend) {
        int pos_n = pos + 8;
        int e_n = 0, src_n = 0, dst_n = 0;
        if (pos_n < eend) {
            e_n = csr_eid[pos_n];
            src_n = ei[e_n];
            dst_n = ei[EE + e_n];
        }
        const float* Pn = &P2[(src_c - n0) * PNODE + o * PST];
        const float* hb = &hbuf[(size_t)e_c * HST];
        float4 hq[9], pq[9];
        #pragma unroll
        for (int b = 0; b < 9; b++) hq[b] = *(const float4*)&hb[4 * b];
        #pragma unroll
        for (int b = 0; b < 9; b++) pq[b] = *(const float4*)&Pn[4 * b];
        float msg = 0.f;
        #pragma unroll
        for (int b = 0; b < 9; b++)
            msg += hq[b].x * pq[b].x + hq[b].y * pq[b].y
                 + hq[b].z * pq[b].z + hq[b].w * pq[b].w;
        atomicAdd(&agg[(size_t)dst_c * 32 + o], msg);
        pos = pos_n; e_c = e_n; src_c = src_n; dst_c = dst_n;
    }
}

// ---------------- combine: agg/cnt + x@root + bias -> BN -> ReLU ----------------
// R6: psum contributions run-aggregated per block (batch sorted -> 8 nodes
// share 1-2 graphs) to kill same-line atomic serialization.
__global__ __launch_bounds__(256) void k_combine(const float* __restrict__ x_in,
        const float* __restrict__ agg, const int* __restrict__ cnt,
        const float* __restrict__ root, const float* __restrict__ bias,
        const float* __restrict__ bng, const float* __restrict__ bnb,
        const float* __restrict__ bnm, const float* __restrict__ bnv,
        float* __restrict__ x_out, float* __restrict__ psum,
        const int* __restrict__ batch) {
    __shared__ float xs[8][32];
    __shared__ float vals[8][32];
    __shared__ int gb[8];
    int t = threadIdx.x;
    int n0 = blockIdx.x * 8;
    xs[t >> 5][t & 31] = x_in[n0 * 32 + t];
    __syncthreads();
    int k = t >> 5, o = t & 31, n = n0 + k;
    float r = bias[o];
    #pragma unroll
    for (int i = 0; i < 32; i++) r += xs[k][i] * root[i * 32 + o];
    float a = agg[(size_t)n * 32 + o] / fmaxf((float)cnt[n], 1.f);
    float val = a + r;
    val = (val - bnm[o]) * rsqrtf(bnv[o] + EPSV) * bng[o] + bnb[o];
    val = fmaxf(val, 0.f);
    if (x_out) x_out[(size_t)n * 32 + o] = val;
    if (psum) {
        vals[k][o] = val;
        if (o == 0) gb[k] = batch[n];
        __syncthreads();
        if (k == 0) {
            float acc = vals[0][o];
            int g = gb[0];
            #pragma unroll
            for (int k2 = 1; k2 < 8; k2++) {
                if (gb[k2] == g) acc += vals[k2][o];
                else {
                    atomicAdd(&psum[(size_t)g * 32 + o], acc);
                    g = gb[k2]; acc = vals[k2][o];
                }
            }
            atomicAdd(&psum[(size_t)g * 32 + o], acc);
        }
    }
}

// ---------------- global mean pool + readout MLP ----------------
// R6: per-graph node counts via binary search over sorted batch (no atomics).
__global__ __launch_bounds__(256) void k_readout(const float* __restrict__ psum,
        const int* __restrict__ batch,
        const float* __restrict__ r1w, const float* __restrict__ r1b,
        const float* __restrict__ r2w, const float* __restrict__ r2b,
        float* __restrict__ out) {
    __shared__ float w1s[32 * 16];
    __shared__ float b1s[16];
    __shared__ float w2s[16];
    __shared__ float ps[GG * 32];
    int t = threadIdx.x;
    int cnt_g = 0;
    if (t < GG) {
        int lo = 0, hi = NN;
        while (lo < hi) { int m = (lo + hi) >> 1; if (batch[m] < t) lo = m + 1; else hi = m; }
        int lb = lo;
        lo = 0; hi = NN;
        while (lo < hi) { int m = (lo + hi) >> 1; if (batch[m] < t + 1) lo = m + 1; else hi = m; }
        cnt_g = lo - lb;
    }
    w1s[t] = r1w[t];
    w1s[t + 256] = r1w[t + 256];
    if (t < 16) { b1s[t] = r1b[t]; w2s[t] = r2w[t]; }
    #pragma unroll
    for (int i = 0; i < GG * 32 / 256; i++) ps[t + i * 256] = psum[t + i * 256];
    __syncthreads();
    if (t < GG) {
        float inv = 1.f / fmaxf((float)cnt_g, 1.f);
        float acc = r2b[0];
        #pragma unroll
        for (int j = 0; j < 16; j++) {
            float dot = 0.f;
            #pragma unroll
            for (int c = 0; c < 32; c++) dot += ps[t * 32 + c] * w1s[c * 16 + j];
            float z = dot * inv + b1s[j];
            acc += fmaxf(z, 0.f) * w2s[j];
        }
        out[t] = acc;
    }
}

extern "C" void kernel_launch(void* const* d_in, const int* in_sizes, int n_in,
                              void* d_out, int out_size, void* d_ws, size_t ws_size,
                              hipStream_t stream) {
    const float* x       = (const float*)d_in[0];
    const float* eattr   = (const float*)d_in[1];
    const float* e1_w1   = (const float*)d_in[2];
    const float* e1_b1   = (const float*)d_in[3];
    const float* e1_w2   = (const float*)d_in[4];
    const float* e1_b2   = (const float*)d_in[5];
    const float* root1   = (const float*)d_in[6];
    const float* bias1   = (const float*)d_in[7];
    const float* e2_w1   = (const float*)d_in[8];
    const float* e2_b1   = (const float*)d_in[9];
    const float* e2_w2   = (const float*)d_in[10];
    const float* e2_b2   = (const float*)d_in[11];
    const float* root2   = (const float*)d_in[12];
    const float* bias2   = (const float*)d_in[13];
    const float* bn1_g   = (const float*)d_in[14];
    const float* bn1_b   = (const float*)d_in[15];
    const float* bn1_m   = (const float*)d_in[16];
    const float* bn1_v   = (const float*)d_in[17];
    const float* bn2_g   = (const float*)d_in[18];
    const float* bn2_b   = (const float*)d_in[19];
    const float* bn2_m   = (const float*)d_in[20];
    const float* bn2_v   = (const float*)d_in[21];
    const float* r1_w    = (const float*)d_in[22];
    const float* r1_b    = (const float*)d_in[23];
    const float* r2_w    = (const float*)d_in[24];
    const float* r2_b    = (const float*)d_in[25];
    const int*   ei      = (const int*)d_in[26];
    const int*   batch   = (const int*)d_in[27];

    // workspace layout (bytes) — zeroed buffers contiguous for a single memset
    char* ws = (char*)d_ws;
    float* hbuf1  = (float*)(ws);                   // 14,400,000
    float* hbuf2  = (float*)(ws + 14400000);        // 14,400,000
    float* w2r1   = (float*)(ws + 28800000);        // 135,168
    float* w2r2   = (float*)(ws + 28935168);        // 135,168
    // ---- zero region start (1,408,192 B) ----
    float* agg    = (float*)(ws + 29070336);        // 1,280,000
    int*   cnt    = (int*)  (ws + 30350336);        // 40,000
    int*   deg    = (int*)  (ws + 30390336);        // 40,000
    int*   cursor = (int*)  (ws + 30430336);        // 40,000
    float* psum   = (float*)(ws + 30470336);        // 8,192
    // ---- zero region end ----
    float* xmid   = (float*)(ws + 30478528);        // 1,280,000
    int*   rowptr = (int*)  (ws + 31758528);        // 40,064
    int*   csr    = (int*)  (ws + 31798592);        // 400,000
    // total ~32.2 MB

    hipMemsetAsync(ws + 29070336, 0, 1408192, stream);   // agg+cnt+deg+cursor+psum

    // CSR build (shared by both layers)
    k_hist<<<(EE + 255) / 256, 256, 0, stream>>>(ei, cnt, deg);
    k_scan<<<1, 1024, 0, stream>>>(deg, rowptr);
    k_scatter<<<(EE + 255) / 256, 256, 0, stream>>>(ei, rowptr, cursor, csr);

    // weight transposes (both layers, one kernel)
    dim3 wgrid((SLOTS + 255) / 256, 32);
    k_w2t<<<wgrid, 256, 0, stream>>>(e1_w2, e1_b2, e2_w2, e2_b2, w2r1, w2r2);

    // per-edge h for both layers
    k_hedge2<<<EE / 8, 256, 0, stream>>>(eattr, e1_w1, e1_b1, e2_w1, e2_b1, hbuf1, hbuf2);

    // ---- layer 1 ----
    k_fused3<<<NN / NB, 256, 0, stream>>>(x, hbuf1, w2r1, ei, rowptr, csr, agg);
    k_combine<<<NN / 8, 256, 0, stream>>>(x, agg, cnt, root1, bias1,
                                          bn1_g, bn1_b, bn1_m, bn1_v,
                                          xmid, nullptr, batch);

    // ---- layer 2 ----
    hipMemsetAsync(agg, 0, NN * 32 * 4, stream);
    k_fused3<<<NN / NB, 256, 0, stream>>>(xmid, hbuf2, w2r2, ei, rowptr, csr, agg);
    k_combine<<<NN / 8, 256, 0, stream>>>(xmid, agg, cnt, root2, bias2,
                                          bn2_g, bn2_b, bn2_m, bn2_v,
                                          nullptr, psum, batch);

    // ---- pool + readout ----
    k_readout<<<1, 256, 0, stream>>>(psum, batch, r1_w, r1_b, r2_w, r2_b, (float*)d_out);
}

// Round 7
// 248.428 us; speedup vs baseline: 2.2274x; 1.0034x over previous
//
#include <hip/hip_runtime.h>

#define NN 10000
#define EE 100000
#define CC 32
#define GG 64
#define EPSV 1e-5f
#define NB 8               // src nodes per fused block
#define SLOTS 1056         // 32*32 P-slots + 32 bias slots (w2r layout [i][slot])
#define HST 36             // h row stride (32 h + 1 one + 3 zero), 144B = 16B-aligned
#define PST 36             // P2 c-stride per o-row (c=0..31 data, 32 bias, 33..35 pad)
#define PNODE (32*PST)     // 1152 floats per node in LDS
#define EBLK (EE/8)        // 12500 edge blocks in k_init
#define WBLK 160           // w2t blocks in k_init: 5 per i, i=0..31

// ---------------- k_init: per-edge h (both layers) + degree hists + weight transpose ----
// R7: merged k_hedge2 + k_hist + k_w2t into one dispatch (block-range split).
__global__ __launch_bounds__(256) void k_init(const float* __restrict__ edge_attr,
        const float* __restrict__ w1a, const float* __restrict__ b1a,
        const float* __restrict__ w1b, const float* __restrict__ b1b,
        const int* __restrict__ ei,
        float* __restrict__ hbuf1, float* __restrict__ hbuf2,
        int* __restrict__ cnt, int* __restrict__ deg,
        const float* __restrict__ w2a, const float* __restrict__ b2a,
        const float* __restrict__ w2b, const float* __restrict__ b2b,
        float* __restrict__ w2r1, float* __restrict__ w2r2) {
    int blk = blockIdx.x;
    int t = threadIdx.x;
    if (blk < EBLK) {
        int e = blk * 8 + (t >> 5);
        int o = t & 31;
        float4 a = *(const float4*)&edge_attr[(size_t)e * 4];
        float ha = fmaxf(a.x * w1a[o] + a.y * w1a[32 + o] + a.z * w1a[64 + o] + a.w * w1a[96 + o] + b1a[o], 0.f);
        float hb = fmaxf(a.x * w1b[o] + a.y * w1b[32 + o] + a.z * w1b[64 + o] + a.w * w1b[96 + o] + b1b[o], 0.f);
        hbuf1[(size_t)e * HST + o] = ha;
        hbuf2[(size_t)e * HST + o] = hb;
        if (o < 4) {
            float pad = (o == 0) ? 1.f : 0.f;
            hbuf1[(size_t)e * HST + 32 + o] = pad;
            hbuf2[(size_t)e * HST + 32 + o] = pad;
        }
        if (o == 0) {
            atomicAdd(&cnt[ei[EE + e]], 1);   // dst in-degree
            atomicAdd(&deg[ei[e]], 1);        // src out-degree
        }
    } else {
        int b2i = blk - EBLK;                 // 0..159
        int s = (b2i % 5) * 256 + t;
        int i = b2i / 5;
        if (s < SLOTS) {
            float va = (s < 1024) ? w2a[(s >> 5) * 1024 + i * 32 + (s & 31)]
                                  : b2a[i * 32 + (s - 1024)];
            float vb = (s < 1024) ? w2b[(s >> 5) * 1024 + i * 32 + (s & 31)]
                                  : b2b[i * 32 + (s - 1024)];
            w2r1[i * SLOTS + s] = va;
            w2r2[i * SLOTS + s] = vb;
        }
    }
}

// ---------------- exclusive scan of deg[NN] -> rowptr[NN+1] AND cursor copy ----------------
__global__ __launch_bounds__(1024) void k_scan(const int* __restrict__ deg,
                                               int* __restrict__ rowptr,
                                               int* __restrict__ cursor) {
    __shared__ int buf[1024];
    int t = threadIdx.x;
    int v[10]; int s = 0;
    int base = t * 10;
    #pragma unroll
    for (int k = 0; k < 10; k++) {
        int idx = base + k;
        v[k] = (idx < NN) ? deg[idx] : 0;
        s += v[k];
    }
    buf[t] = s;
    for (int off = 1; off < 1024; off <<= 1) {
        __syncthreads();
        int val = buf[t] + ((t >= off) ? buf[t - off] : 0);
        __syncthreads();
        buf[t] = val;
    }
    __syncthreads();
    int carry = (t > 0) ? buf[t - 1] : 0;
    #pragma unroll
    for (int k = 0; k < 10; k++) {
        int idx = base + k;
        if (idx < NN) { rowptr[idx] = carry; cursor[idx] = carry; }
        carry += v[k];
    }
    if (t == 1023) rowptr[NN] = buf[1023];
}

// ---------------- scatter edge ids into CSR (cursor holds absolute positions) ----------------
__global__ void k_scatter(const int* __restrict__ ei,
                          int* __restrict__ cursor, int* __restrict__ csr_eid) {
    int e = blockIdx.x * blockDim.x + threadIdx.x;
    if (e >= EE) return;
    int pos = atomicAdd(&cursor[ei[e]], 1);
    csr_eid[pos] = e;
}

// ---------------- fused NNConv: P in LDS + edge pass (R5 structure, R7 h-prefetch) -------
__global__ __launch_bounds__(256, 3) void k_fused3(const float* __restrict__ x,
        const float* __restrict__ hbuf,
        const float* __restrict__ w2r,
        const int* __restrict__ ei, const int* __restrict__ rowptr,
        const int* __restrict__ csr_eid, float* __restrict__ agg) {
    __shared__ float xs[NB][32];
    __shared__ float P2[NB * PNODE];     // 8*1152*4 = 36,864 B
    int t = threadIdx.x;
    int o = t & 31;
    int cb = 4 * (t >> 5);               // base c (0,4,...,28)
    int n0 = blockIdx.x * NB;

    xs[t >> 5][t & 31] = x[n0 * 32 + t];
    __syncthreads();

    // ---- Phase A: P2[n][o][c] = sum_i x[n,i] * w2r[i][c*32+o] ----
    {
        float acc[4][NB];
        #pragma unroll
        for (int k = 0; k < 4; k++)
            #pragma unroll
            for (int n = 0; n < NB; n++) acc[k][n] = 0.f;
        #pragma unroll
        for (int j = 0; j < 8; j++) {
            float wk[4][4];
            #pragma unroll
            for (int r = 0; r < 4; r++)
                #pragma unroll
                for (int k = 0; k < 4; k++)
                    wk[r][k] = w2r[(4 * j + r) * SLOTS + (cb + k) * 32 + o];
            #pragma unroll
            for (int n = 0; n < NB; n++) {
                float4 xq = *(const float4*)&xs[n][4 * j];
                #pragma unroll
                for (int k = 0; k < 4; k++)
                    acc[k][n] += xq.x * wk[0][k] + xq.y * wk[1][k]
                               + xq.z * wk[2][k] + xq.w * wk[3][k];
            }
        }
        #pragma unroll
        for (int n = 0; n < NB; n++) {
            float4 st = make_float4(acc[0][n], acc[1][n], acc[2][n], acc[3][n]);
            *(float4*)&P2[n * PNODE + o * PST + cb] = st;
        }
    }
    if (t < 32) {
        float wb[32];
        #pragma unroll
        for (int i = 0; i < 32; i++) wb[i] = w2r[i * SLOTS + 1024 + t];
        #pragma unroll
        for (int n = 0; n < NB; n++) {
            float b = 0.f;
            #pragma unroll
            for (int j = 0; j < 8; j++) {
                float4 xq = *(const float4*)&xs[n][4 * j];
                b += xq.x * wb[4 * j] + xq.y * wb[4 * j + 1]
                   + xq.z * wb[4 * j + 2] + xq.w * wb[4 * j + 3];
            }
            *(float4*)&P2[n * PNODE + t * PST + 32] = make_float4(b, 0.f, 0.f, 0.f);
        }
    }
    __syncthreads();

    // ---- Phase B: 32-lane group per edge; h prefetched one edge ahead ----
    int ebase = rowptr[n0];
    int eend  = rowptr[n0 + NB];
    int grp = t >> 5;
    int pos = ebase + grp;
    int e_c = 0, src_c = 0, dst_c = 0;
    float4 hq[9];
    if (pos < eend) {
        e_c = csr_eid[pos];
        src_c = ei[e_c];
        dst_c = ei[EE + e_c];
        const float* hb = &hbuf[(size_t)e_c * HST];
        #pragma unroll
        for (int b = 0; b < 9; b++) hq[b] = *(const float4*)&hb[4 * b];
    }
    while (pos < eend) {
        int pos_n = pos + 8;
        int e_n = 0, src_n = 0, dst_n = 0;
        float4 hq_n[9];
        if (pos_n < eend) {                     // prefetch next edge: indices + h data
            e_n = csr_eid[pos_n];
            src_n = ei[e_n];
            dst_n = ei[EE + e_n];
            const float* hbn = &hbuf[(size_t)e_n * HST];
            #pragma unroll
            for (int b = 0; b < 9; b++) hq_n[b] = *(const float4*)&hbn[4 * b];
        }
        const float* Pn = &P2[(src_c - n0) * PNODE + o * PST];
        float msg = 0.f;
        #pragma unroll
        for (int b = 0; b < 9; b++) {
            float4 pq = *(const float4*)&Pn[4 * b];      // ds_read_b128
            msg += hq[b].x * pq.x + hq[b].y * pq.y
                 + hq[b].z * pq.z + hq[b].w * pq.w;
        }
        atomicAdd(&agg[(size_t)dst_c * 32 + o], msg);
        pos = pos_n; e_c = e_n; src_c = src_n; dst_c = dst_n;
        #pragma unroll
        for (int b = 0; b < 9; b++) hq[b] = hq_n[b];
    }
}

// ---------------- combine: agg/cnt + x@root + bias -> BN -> ReLU ----------------
// Layer 1 (x_out != null): also zeroes agg in place for layer 2 (saves a memset dispatch).
// Layer 2 (psum != null): block-level run-aggregation before psum atomics.
__global__ __launch_bounds__(256) void k_combine(const float* __restrict__ x_in,
        float* __restrict__ agg, const int* __restrict__ cnt,
        const float* __restrict__ root, const float* __restrict__ bias,
        const float* __restrict__ bng, const float* __restrict__ bnb,
        const float* __restrict__ bnm, const float* __restrict__ bnv,
        float* __restrict__ x_out, float* __restrict__ psum,
        const int* __restrict__ batch) {
    __shared__ float xs[8][32];
    __shared__ float vals[8][32];
    __shared__ int gb[8];
    int t = threadIdx.x;
    int n0 = blockIdx.x * 8;
    xs[t >> 5][t & 31] = x_in[n0 * 32 + t];
    __syncthreads();
    int k = t >> 5, o = t & 31, n = n0 + k;
    float r = bias[o];
    #pragma unroll
    for (int i = 0; i < 32; i++) r += xs[k][i] * root[i * 32 + o];
    float a = agg[(size_t)n * 32 + o] / fmaxf((float)cnt[n], 1.f);
    float val = a + r;
    val = (val - bnm[o]) * rsqrtf(bnv[o] + EPSV) * bng[o] + bnb[o];
    val = fmaxf(val, 0.f);
    if (x_out) {
        x_out[(size_t)n * 32 + o] = val;
        agg[(size_t)n * 32 + o] = 0.f;        // re-zero for layer 2
    }
    if (psum) {
        vals[k][o] = val;
        if (o == 0) gb[k] = batch[n];
        __syncthreads();
        if (k == 0) {
            float acc = vals[0][o];
            int g = gb[0];
            #pragma unroll
            for (int k2 = 1; k2 < 8; k2++) {
                if (gb[k2] == g) acc += vals[k2][o];
                else {
                    atomicAdd(&psum[(size_t)g * 32 + o], acc);
                    g = gb[k2]; acc = vals[k2][o];
                }
            }
            atomicAdd(&psum[(size_t)g * 32 + o], acc);
        }
    }
}

// ---------------- global mean pool + readout MLP ----------------
__global__ __launch_bounds__(256) void k_readout(const float* __restrict__ psum,
        const int* __restrict__ batch,
        const float* __restrict__ r1w, const float* __restrict__ r1b,
        const float* __restrict__ r2w, const float* __restrict__ r2b,
        float* __restrict__ out) {
    __shared__ float w1s[32 * 16];
    __shared__ float b1s[16];
    __shared__ float w2s[16];
    __shared__ float ps[GG * 32];
    int t = threadIdx.x;
    int cnt_g = 0;
    if (t < GG) {
        int lo = 0, hi = NN;
        while (lo < hi) { int m = (lo + hi) >> 1; if (batch[m] < t) lo = m + 1; else hi = m; }
        int lb = lo;
        lo = 0; hi = NN;
        while (lo < hi) { int m = (lo + hi) >> 1; if (batch[m] < t + 1) lo = m + 1; else hi = m; }
        cnt_g = lo - lb;
    }
    w1s[t] = r1w[t];
    w1s[t + 256] = r1w[t + 256];
    if (t < 16) { b1s[t] = r1b[t]; w2s[t] = r2w[t]; }
    #pragma unroll
    for (int i = 0; i < GG * 32 / 256; i++) ps[t + i * 256] = psum[t + i * 256];
    __syncthreads();
    if (t < GG) {
        float inv = 1.f / fmaxf((float)cnt_g, 1.f);
        float acc = r2b[0];
        #pragma unroll
        for (int j = 0; j < 16; j++) {
            float dot = 0.f;
            #pragma unroll
            for (int c = 0; c < 32; c++) dot += ps[t * 32 + c] * w1s[c * 16 + j];
            float z = dot * inv + b1s[j];
            acc += fmaxf(z, 0.f) * w2s[j];
        }
        out[t] = acc;
    }
}

extern "C" void kernel_launch(void* const* d_in, const int* in_sizes, int n_in,
                              void* d_out, int out_size, void* d_ws, size_t ws_size,
                              hipStream_t stream) {
    const float* x       = (const float*)d_in[0];
    const float* eattr   = (const float*)d_in[1];
    const float* e1_w1   = (const float*)d_in[2];
    const float* e1_b1   = (const float*)d_in[3];
    const float* e1_w2   = (const float*)d_in[4];
    const float* e1_b2   = (const float*)d_in[5];
    const float* root1   = (const float*)d_in[6];
    const float* bias1   = (const float*)d_in[7];
    const float* e2_w1   = (const float*)d_in[8];
    const float* e2_b1   = (const float*)d_in[9];
    const float* e2_w2   = (const float*)d_in[10];
    const float* e2_b2   = (const float*)d_in[11];
    const float* root2   = (const float*)d_in[12];
    const float* bias2   = (const float*)d_in[13];
    const float* bn1_g   = (const float*)d_in[14];
    const float* bn1_b   = (const float*)d_in[15];
    const float* bn1_m   = (const float*)d_in[16];
    const float* bn1_v   = (const float*)d_in[17];
    const float* bn2_g   = (const float*)d_in[18];
    const float* bn2_b   = (const float*)d_in[19];
    const float* bn2_m   = (const float*)d_in[20];
    const float* bn2_v   = (const float*)d_in[21];
    const float* r1_w    = (const float*)d_in[22];
    const float* r1_b    = (const float*)d_in[23];
    const float* r2_w    = (const float*)d_in[24];
    const float* r2_b    = (const float*)d_in[25];
    const int*   ei      = (const int*)d_in[26];
    const int*   batch   = (const int*)d_in[27];

    // workspace layout (bytes) — zeroed buffers contiguous for a single memset
    char* ws = (char*)d_ws;
    float* hbuf1  = (float*)(ws);                   // 14,400,000
    float* hbuf2  = (float*)(ws + 14400000);        // 14,400,000
    float* w2r1   = (float*)(ws + 28800000);        // 135,168
    float* w2r2   = (float*)(ws + 28935168);        // 135,168
    // ---- zero region start (1,368,192 B) ----
    float* agg    = (float*)(ws + 29070336);        // 1,280,000
    int*   cnt    = (int*)  (ws + 30350336);        // 40,000
    int*   deg    = (int*)  (ws + 30390336);        // 40,000
    float* psum   = (float*)(ws + 30430336);        // 8,192
    // ---- zero region end ----
    float* xmid   = (float*)(ws + 30438528);        // 1,280,000
    int*   rowptr = (int*)  (ws + 31718528);        // 40,064
    int*   cursor = (int*)  (ws + 31758592);        // 40,000
    int*   csr    = (int*)  (ws + 31798592);        // 400,000
    // total ~32.2 MB

    hipMemsetAsync(ws + 29070336, 0, 1368192, stream);   // agg+cnt+deg+psum

    // h (both layers) + degree hists + weight transposes — one dispatch
    k_init<<<EBLK + WBLK, 256, 0, stream>>>(eattr, e1_w1, e1_b1, e2_w1, e2_b1, ei,
                                            hbuf1, hbuf2, cnt, deg,
                                            e1_w2, e1_b2, e2_w2, e2_b2, w2r1, w2r2);
    k_scan<<<1, 1024, 0, stream>>>(deg, rowptr, cursor);
    k_scatter<<<(EE + 255) / 256, 256, 0, stream>>>(ei, cursor, csr);

    // ---- layer 1 ----
    k_fused3<<<NN / NB, 256, 0, stream>>>(x, hbuf1, w2r1, ei, rowptr, csr, agg);
    k_combine<<<NN / 8, 256, 0, stream>>>(x, agg, cnt, root1, bias1,
                                          bn1_g, bn1_b, bn1_m, bn1_v,
                                          xmid, nullptr, batch);

    // ---- layer 2 ----
    k_fused3<<<NN / NB, 256, 0, stream>>>(xmid, hbuf2, w2r2, ei, rowptr, csr, agg);
    k_combine<<<NN / 8, 256, 0, stream>>>(xmid, agg, cnt, root2, bias2,
                                          bn2_g, bn2_b, bn2_m, bn2_v,
                                          nullptr, psum, batch);

    // ---- pool + readout ----
    k_readout<<<1, 256, 0, stream>>>(psum, batch, r1_w, r1_b, r2_w, r2_b, (float*)d_out);
}